// Round 2
// baseline (202.471 us; speedup 1.0000x reference)
//
#include <hip/hip_runtime.h>

// Reprojection residual, round 2.
//
// Round-1 lesson: 28 random-cidx scalar loads/thread through L1 serialized on
// unique cache lines (~55 lines per wave64 load) and thrashed the 32 KB L1
// (table is 56 KB) -> 78 us with every pipe idle.
//
// Fix: persistent blocks stage the whole pose table into LDS once, padded
// 7->8 floats so each pose gather is 2x ds_read_b128. Parity swizzle on the
// float4 slot index spreads random-cidx accesses over all 32 banks
// (unswizzled, slot starts land only on banks {0,8,16,24} -> 2x serialization).
//
// Occupancy: 1024 thr/block, 62.5 KB LDS -> 2 blocks/CU = 2048 thr/CU (max).

#define BLOCK 1024
#define GRID  512   // 2 blocks/CU x 256 CU

__global__ __launch_bounds__(BLOCK) void residual_kernel(
    const float* __restrict__ poses,
    const float* __restrict__ pts,
    const float* __restrict__ obs,
    const float* __restrict__ Km,
    const int*   __restrict__ cidx,
    const int*   __restrict__ pidx,
    float*       __restrict__ out,
    int n4,   // number of 4-point groups
    int C)    // number of poses
{
    extern __shared__ float spose[];   // C * 8 floats, parity-swizzled

    // ---- Stage pose table into LDS (coalesced global reads) ----
    int tid = threadIdx.x;
    int total = C * 7;
    for (int idx = tid; idx < total; idx += BLOCK) {
        int j = idx / 7;            // pose id (compiler magic-div)
        int k = idx - j * 7;        // component 0..6
        // pose j -> float4 slots {2j + par, 2j + 1 - par}, par = j&1
        int par  = j & 1;
        int slot = (k < 4) ? (2 * j + par) : (2 * j + 1 - par);
        int off  = (k < 4) ? k : (k - 4);
        spose[slot * 4 + off] = poses[idx];
    }
    __syncthreads();

    const float4* sp = (const float4*)spose;

    // Wave-uniform K
    float k00 = Km[0], k01 = Km[1], k02 = Km[2];
    float k10 = Km[3], k11 = Km[4], k12 = Km[5];
    float k20 = Km[6], k21 = Km[7], k22 = Km[8];

    int stride = GRID * BLOCK;
    for (int t = blockIdx.x * BLOCK + tid; t < n4; t += stride) {
        int4 ci4 = ((const int4*)cidx)[t];
        int4 pi4 = ((const int4*)pidx)[t];
        float4 ob01 = ((const float4*)obs)[2 * t];
        float4 ob23 = ((const float4*)obs)[2 * t + 1];

        int cis[4]  = {ci4.x, ci4.y, ci4.z, ci4.w};
        int pis[4]  = {pi4.x, pi4.y, pi4.z, pi4.w};
        float ob[8] = {ob01.x, ob01.y, ob01.z, ob01.w,
                       ob23.x, ob23.y, ob23.z, ob23.w};

        float res[8];

        #pragma unroll
        for (int j = 0; j < 4; ++j) {
            const float* pp = pts + 3L * (long)pis[j];
            float px = pp[0], py = pp[1], pz = pp[2];

            int ci  = cis[j];
            int par = ci & 1;
            float4 lo = sp[2 * ci + par];        // {tx,ty,tz,qx}
            float4 hi = sp[2 * ci + 1 - par];    // {qy,qz,qw,pad}
            float tx = lo.x, ty = lo.y, tz = lo.z;
            float qx = lo.w, qy = hi.x, qz = hi.y, qw = hi.z;

            // uv = cross(qv, p) + qw * p
            float ux = qy * pz - qz * py + qw * px;
            float uy = qz * px - qx * pz + qw * py;
            float uz = qx * py - qy * px + qw * pz;

            // pc = p + 2*cross(qv, uv) + t
            float cx = px + 2.0f * (qy * uz - qz * uy) + tx;
            float cy = py + 2.0f * (qz * ux - qx * uz) + ty;
            float cz = pz + 2.0f * (qx * uy - qy * ux) + tz;

            // proj = K @ pc ; pix = proj.xy / proj.z ; res = pix - obs
            float w    = k20 * cx + k21 * cy + k22 * cz;
            float invw = 1.0f / w;
            float u    = (k00 * cx + k01 * cy + k02 * cz) * invw;
            float v    = (k10 * cx + k11 * cy + k12 * cz) * invw;

            res[2 * j]     = u - ob[2 * j];
            res[2 * j + 1] = v - ob[2 * j + 1];
        }

        float4* o = (float4*)(out + 8L * (long)t);
        o[0] = make_float4(res[0], res[1], res[2], res[3]);
        o[1] = make_float4(res[4], res[5], res[6], res[7]);
    }
}

extern "C" void kernel_launch(void* const* d_in, const int* in_sizes, int n_in,
                              void* d_out, int out_size, void* d_ws, size_t ws_size,
                              hipStream_t stream) {
    const float* poses = (const float*)d_in[0];
    const float* pts   = (const float*)d_in[1];
    const float* obs   = (const float*)d_in[2];
    const float* Km    = (const float*)d_in[3];
    const int*   cidx  = (const int*)d_in[4];
    const int*   pidx  = (const int*)d_in[5];
    float* out = (float*)d_out;

    int P  = in_sizes[4];       // number of points
    int n4 = P / 4;             // P = 5,000,000 -> divisible by 4
    int C  = in_sizes[0] / 7;   // number of poses (2000)

    size_t lds_bytes = (size_t)C * 8 * sizeof(float);  // 64,000 B
    residual_kernel<<<GRID, BLOCK, lds_bytes, stream>>>(
        poses, pts, obs, Km, cidx, pidx, out, n4, C);
}